// Round 13
// baseline (293.541 us; speedup 1.0000x reference)
//
#include <hip/hip_runtime.h>
#include <math.h>

#define N_TOK 4098
#define NK_TOK 4099
#define C_DIM 384
#define NKPAD 4160
#define NSLICE 5
// HEADS = 6, HD = 64

typedef short  bh8 __attribute__((ext_vector_type(8)));   // 8 bf16 (4 VGPRs)
typedef float  f32x4 __attribute__((ext_vector_type(4)));
typedef unsigned short ushort;
typedef ushort u4 __attribute__((ext_vector_type(4)));
typedef ushort u8 __attribute__((ext_vector_type(8)));

static __device__ __forceinline__ ushort f2bf(float f) {
  unsigned int u = __float_as_uint(f);
  u = (u + 0x7FFF + ((u >> 16) & 1)) >> 16;   // RNE
  return (ushort)u;
}
static __device__ __forceinline__ float bf2f(ushort s) {
  return __uint_as_float(((unsigned int)s) << 16);
}

// Q scale: D^-0.5 * log2(e), folded into Wq at prep; attention exp = exp2
#define QSCALE 0.18033688011112042f

// ---------------------------------------------------------------------------
// prep: blocks 0..259 build bf16 Ak/Av rows (16 rows each; row 4098 computed
// by the 12 gemm3 blocks that consume it); blocks 260..291 convert W
// (Wq prescaled by QSCALE); block 292: zero merge counters + keep-compaction
// prefix scan -> inv[], nk; blocks 293..356: pool partials (64 rows each).
__global__ __launch_bounds__(256) void prep_kernel(
    const float* __restrict__ x, const float* __restrict__ pos,
    const float* __restrict__ Wq, const float* __restrict__ Wk,
    const float* __restrict__ Wv, const float* __restrict__ Wp,
    const float* __restrict__ mask, const float* __restrict__ mask_block,
    ushort* __restrict__ Ak, ushort* __restrict__ Av,
    ushort* __restrict__ Wb, int* __restrict__ nk, int* __restrict__ inv,
    float* __restrict__ pooled_part, float* __restrict__ cnt_part,
    int* __restrict__ mergeCnt) {
  const int b = blockIdx.x, t = threadIdx.x;
  if (b < 260) {
    const int r0 = b * 16;
#pragma unroll
    for (int i = 0; i < 6; ++i) {
      const int idx = i * 1024 + t * 4;
      const int row = r0 + idx / C_DIM, col = idx % C_DIM;
      if (row >= NK_TOK - 1) continue;       // row 4098 computed in gemm3
      const float4 pv = *(const float4*)&pos[(size_t)row * C_DIM + col];
      const float4 xv = *(const float4*)&x[(size_t)row * C_DIM + col];
      u4 k4 = {f2bf(xv.x + pv.x), f2bf(xv.y + pv.y),
               f2bf(xv.z + pv.z), f2bf(xv.w + pv.w)};
      *(u4*)&Ak[(size_t)row * C_DIM + col] = k4;
      u4 v4 = {f2bf(xv.x), f2bf(xv.y), f2bf(xv.z), f2bf(xv.w)};
      *(u4*)&Av[(size_t)row * C_DIM + col] = v4;
    }
  } else if (b < 292) {
    const int wi = b - 260;                  // 0..31; 8 blocks per weight
    const float* src = (wi < 8) ? Wq : (wi < 16) ? Wk : (wi < 24) ? Wv : Wp;
    const float sc = (wi < 8) ? QSCALE : 1.f;  // fold Q prescale into Wq
    const int base = (wi >> 3) * 147456 + (wi & 7) * 18432;
#pragma unroll 2
    for (int i = 0; i < 18; ++i) {
      const int g = base + i * 1024 + t * 4;
      const float4 v = *(const float4*)&src[(wi & 7) * 18432 + i * 1024 + t * 4];
      u4 o = {f2bf(v.x * sc), f2bf(v.y * sc), f2bf(v.z * sc), f2bf(v.w * sc)};
      *(u4*)&Wb[g] = o;
    }
  } else if (b == 292) {
    if (t < 102) mergeCnt[t] = 0;            // 17 q-tiles x 6 heads
    // keep-compaction: 256 threads x 17 elements, block prefix scan
    __shared__ int scnt[256];
    const int j0 = t * 17;
    unsigned int bits = 0;
    int c = 0;
#pragma unroll 1
    for (int u = 0; u < 17; ++u) {
      const int j = j0 + u;
      bool keep = false;
      if (j < NK_TOK)
        keep = (j >= 1 && j <= N_TOK - 2) ? (mask[j - 1] >= 0.5f)
                                          : (mask_block[j] >= 0.5f);
      if (keep) { bits |= 1u << u; ++c; }
    }
    scnt[t] = c;
    __syncthreads();
    for (int d = 1; d < 256; d <<= 1) {
      const int v = scnt[t];
      const int add = (t >= d) ? scnt[t - d] : 0;
      __syncthreads();
      scnt[t] = v + add;
      __syncthreads();
    }
    int base = scnt[t] - c;                  // exclusive prefix
    if (t == 255) *nk = scnt[255];
#pragma unroll 1
    for (int u = 0; u < 17; ++u) {
      const int j = j0 + u;
      if (j < NK_TOK) inv[j] = ((bits >> u) & 1) ? base++ : -1;
    }
  } else {
    // pool partials: 64 blocks x 64 mask-rows; threads 0..127 cover 2 chans
    const int pb = b - 293;
    const int r0 = pb * 64;
    float acc0 = 0.f, acc1 = 0.f;
    int lc = 0;
    for (int r = r0; r < r0 + 64; ++r) {
      if (mask[r] < 0.5f) {
        acc0 += x[(size_t)(r + 1) * C_DIM + t];
        if (t < 128) acc1 += x[(size_t)(r + 1) * C_DIM + 256 + t];
        ++lc;
      }
    }
    pooled_part[pb * C_DIM + t] = acc0;
    if (t < 128) pooled_part[pb * C_DIM + 256 + t] = acc1;
    if (t == 0) cnt_part[pb] = (float)lc;
  }
}

// ---------------------------------------------------------------------------
// bf16 MFMA GEMM core: 64x64 out tile, K=384, BK=64, synchronous u8 staging
// with VGPR prefetch of the next K-chunk during compute. Padded LDS [64][72].
static __device__ __forceinline__ void gemm_core(
    const ushort* __restrict__ A, const ushort* __restrict__ B,
    ushort (* __restrict__ As)[72], ushort (* __restrict__ Bs)[72],
    int t, int w, int quad, int l15, f32x4 acc[4]) {
  const int g = t & 7;
  u8 ra[2], rb[2];
#pragma unroll
  for (int it = 0; it < 2; ++it) {
    const int r = it * 32 + (t >> 3);
    ra[it] = *(const u8*)&A[r * C_DIM + g * 8];
    rb[it] = *(const u8*)&B[r * C_DIM + g * 8];
  }
#pragma unroll 1
  for (int kt = 0; kt < 6; ++kt) {
    __syncthreads();                         // previous chunk's readers done
#pragma unroll
    for (int it = 0; it < 2; ++it) {
      const int r = it * 32 + (t >> 3);
      *(u8*)&As[r][g * 8] = ra[it];
      *(u8*)&Bs[r][g * 8] = rb[it];
    }
    __syncthreads();
    if (kt < 5) {
      const int k0 = (kt + 1) * 64;
#pragma unroll
      for (int it = 0; it < 2; ++it) {
        const int r = it * 32 + (t >> 3);
        ra[it] = *(const u8*)&A[r * C_DIM + k0 + g * 8];
        rb[it] = *(const u8*)&B[r * C_DIM + k0 + g * 8];
      }
    }
    const bh8 b0 = *(const bh8*)&Bs[w * 16 + l15][quad * 8];
    const bh8 b1 = *(const bh8*)&Bs[w * 16 + l15][32 + quad * 8];
#pragma unroll
    for (int mb = 0; mb < 4; ++mb) {
      const bh8 a0 = *(const bh8*)&As[mb * 16 + l15][quad * 8];
      const bh8 a1 = *(const bh8*)&As[mb * 16 + l15][32 + quad * 8];
      acc[mb] = __builtin_amdgcn_mfma_f32_16x16x32_bf16(a0, b0, acc[mb], 0, 0, 0);
      acc[mb] = __builtin_amdgcn_mfma_f32_16x16x32_bf16(a1, b1, acc[mb], 0, 0, 0);
    }
  }
}

// fused Q/K/V projection. y = which*6 + h. Q uses Ak with QSCALE-folded Wq.
// The 12 blocks (x==64, which>=1) that consume Ak/Av row 4098 compute the
// back token themselves in a prologue, write it to global, then
// __syncthreads (drains vmcnt -> own-block L2 visibility) before staging.
// Q-pass blocks read poison in row 4098 -- row-local in MFMA, dropped by
// the m<N_TOK store guard (same property rows 4099..4159 rely on).
// K epilogue scatters compacted rows via inv[]; V writes transposed Vt.
__global__ __launch_bounds__(256) void gemm3_kernel(
    ushort* __restrict__ Ak, ushort* __restrict__ Av,
    const ushort* __restrict__ Wb, const int* __restrict__ inv,
    const float* __restrict__ pooled_part, const float* __restrict__ cnt_part,
    const float* __restrict__ pos,
    ushort* __restrict__ Qh, ushort* __restrict__ Kc, ushort* __restrict__ Vt) {
  __shared__ ushort As[64][72], Bs[64][72];
  const int t = threadIdx.x, w = t >> 6, lane = t & 63;
  const int quad = lane >> 4, l15 = lane & 15;
  const int m0 = blockIdx.x * 64;
  const int which = blockIdx.y / 6, h = blockIdx.y % 6;

  if (blockIdx.x == 64 && which >= 1) {      // back token -> row 4098
    float cs = 0.f;
#pragma unroll
    for (int p = 0; p < 64; ++p) cs += cnt_part[p];
    const float ic = 1.f / (cs + 1e-10f);
    for (int c = t; c < C_DIM; c += 256) {
      float s = 0.f;
      for (int p = 0; p < 64; ++p) s += pooled_part[p * C_DIM + c];
      const float back = s * ic;
      const size_t off = (size_t)(NK_TOK - 1) * C_DIM + c;
      if (which == 1) Ak[off] = f2bf(back + pos[off]);
      else            Av[off] = f2bf(back);
    }
    __syncthreads();                         // writes visible to own staging
  }

  const ushort* A = (which == 2 ? Av : Ak) + (size_t)m0 * C_DIM;
  const ushort* B = Wb + (size_t)which * 147456 + (size_t)h * 64 * C_DIM;
  f32x4 acc[4];
#pragma unroll
  for (int i = 0; i < 4; ++i) acc[i] = (f32x4){0.f, 0.f, 0.f, 0.f};
  gemm_core(A, B, As, Bs, t, w, quad, l15, acc);
  const int n = w * 16 + l15;
  if (which == 0) {
#pragma unroll
    for (int mb = 0; mb < 4; ++mb)
#pragma unroll
      for (int r = 0; r < 4; ++r) {
        const int m = m0 + mb * 16 + quad * 4 + r;
        if (m < N_TOK) Qh[((size_t)h * N_TOK + m) * 64 + n] = f2bf(acc[mb][r]);
      }
  } else if (which == 1) {
#pragma unroll
    for (int mb = 0; mb < 4; ++mb)
#pragma unroll
      for (int r = 0; r < 4; ++r) {
        const int m = m0 + mb * 16 + quad * 4 + r;
        if (m < NK_TOK) {
          const int slot = inv[m];
          if (slot >= 0) Kc[((size_t)h * NKPAD + slot) * 64 + n] = f2bf(acc[mb][r]);
        }
      }
  } else {
    // V: write transposed layout [h][d=n][slot] directly (fused vtrans)
#pragma unroll
    for (int mb = 0; mb < 4; ++mb)
#pragma unroll
      for (int r = 0; r < 4; ++r) {
        const int m = m0 + mb * 16 + quad * 4 + r;
        if (m < NK_TOK) {
          const int slot = inv[m];
          if (slot >= 0) Vt[((size_t)h * 64 + n) * NKPAD + slot] = f2bf(acc[mb][r]);
        }
      }
  }
}

// output projection: fp32 out + bias
__global__ __launch_bounds__(256) void gemm_out_kernel(
    const ushort* __restrict__ Am, const ushort* __restrict__ Wpb,
    const float* __restrict__ bp, float* __restrict__ out) {
  __shared__ ushort As[64][72], Bs[64][72];
  const int t = threadIdx.x, w = t >> 6, lane = t & 63;
  const int quad = lane >> 4, l15 = lane & 15;
  const int m0 = blockIdx.x * 64;
  const int h = blockIdx.y;
  f32x4 acc[4];
#pragma unroll
  for (int i = 0; i < 4; ++i) acc[i] = (f32x4){0.f, 0.f, 0.f, 0.f};
  gemm_core(Am + (size_t)m0 * C_DIM, Wpb + (size_t)h * 64 * C_DIM,
            As, Bs, t, w, quad, l15, acc);
  const int n = w * 16 + l15;
  const float bb = bp[h * 64 + n];
#pragma unroll
  for (int mb = 0; mb < 4; ++mb)
#pragma unroll
    for (int r = 0; r < 4; ++r) {
      const int m = m0 + mb * 16 + quad * 4 + r;
      if (m < N_TOK) out[(size_t)m * C_DIM + h * 64 + n] = acc[mb][r] + bb;
    }
}

// ---------------------------------------------------------------------------
// MFMA flash attention: 8 waves x 32 q = 256 q per block (R12 structure:
// full-chunk unguarded softmax fast path). NEW: (a) csum shuffle-reduce
// hoisted out of the chunk loop (per-lane partials, one reduce in epilogue
// -- associative); (b) merge FUSED via split-K finisher: after writing
// partials, fence + device-scope atomicAdd on a per-(qtile,h) counter;
// the 5th arriver ((old+1)%NSLICE==0, replay-robust) acquires and reduces
// all slices' Opart/Lpart -> Am. Counter zeroed in prep (same stream).
// grid (17 q-tiles of 256, 6 heads, NSLICE=5) = 510 blocks.
__global__ __launch_bounds__(512) void attn_kernel(
    const ushort* __restrict__ Qh, const ushort* __restrict__ Kc,
    const ushort* __restrict__ Vt, const int* __restrict__ nkp,
    ushort* __restrict__ Opart, float* __restrict__ Lpart,
    int* __restrict__ mergeCnt, ushort* __restrict__ Am) {
  __shared__ ushort Ks[64][72];      // [slot][d]
  __shared__ ushort Vs[64][72];      // [d][slot]
  __shared__ ushort Ps[8][32][72];   // per-wave P^T staging, 2 q-frags
  const int t = threadIdx.x, w = t >> 6, lane = t & 63;
  const int quad = lane >> 4, l15 = lane & 15;
  const int h = blockIdx.y, slice = blockIdx.z;
  const int q0 = blockIdx.x * 256;
  const int nk = *nkp, nchunk = (nk + 63) >> 6;
  const int g = t & 7;
  const int sr = t >> 3;             // 0..63 staging row (512 threads)

  bh8 qf[2][2];
#pragma unroll
  for (int qa = 0; qa < 2; ++qa) {
    int qr = q0 + w * 32 + qa * 16 + l15;
    if (qr > N_TOK - 1) qr = N_TOK - 1;      // clamp (stores guarded)
    const ushort* qp = Qh + ((size_t)h * N_TOK + qr) * 64 + quad * 8;
    qf[qa][0] = *(const bh8*)qp;
    qf[qa][1] = *(const bh8*)(qp + 32);
  }
  f32x4 oacc[2][4];
#pragma unroll
  for (int qa = 0; qa < 2; ++qa)
#pragma unroll
    for (int i = 0; i < 4; ++i) oacc[qa][i] = (f32x4){0.f, 0.f, 0.f, 0.f};
  float l_r[2] = {0.f, 0.f};         // per-lane partials; reduced in epilogue

  const ushort* kb = Kc + (size_t)h * NKPAD * 64;
  const ushort* vb = Vt + (size_t)h * 64 * NKPAD;

  // loop-carried staging pointers (strength-reduced addressing)
  const ushort* kstage = kb + ((size_t)slice * 64 + sr) * 64 + g * 8;
  const ushort* vstage = vb + (size_t)sr * NKPAD + slice * 64 + g * 8;

  u8 rk, rv;
  if (slice < nchunk) {
    rk = *(const u8*)kstage;
    rv = *(const u8*)vstage;
  }
#pragma unroll 1
  for (int kc = slice; kc < nchunk; kc += NSLICE) {
    __syncthreads();                          // previous chunk's readers done
    *(u8*)&Ks[sr][g * 8] = rk;
    *(u8*)&Vs[sr][g * 8] = rv;
    __syncthreads();
    if (kc + NSLICE < nchunk) {               // prefetch next chunk into VGPRs
      kstage += NSLICE * 64 * 64;
      vstage += NSLICE * 64;
      rk = *(const u8*)kstage;
      rv = *(const u8*)vstage;
    }
    if ((kc + 1) * 64 <= nk) {
      // FULL chunk (all 64 slots valid): unguarded softmax fast path
#pragma unroll
      for (int f = 0; f < 4; ++f) {
        const bh8 a0 = *(const bh8*)&Ks[f * 16 + l15][quad * 8];
        const bh8 a1 = *(const bh8*)&Ks[f * 16 + l15][32 + quad * 8];
        f32x4 s4[2];
#pragma unroll
        for (int qa = 0; qa < 2; ++qa) {
          s4[qa] = (f32x4){0.f, 0.f, 0.f, 0.f};
          s4[qa] = __builtin_amdgcn_mfma_f32_16x16x32_bf16(a0, qf[qa][0], s4[qa], 0, 0, 0);
          s4[qa] = __builtin_amdgcn_mfma_f32_16x16x32_bf16(a1, qf[qa][1], s4[qa], 0, 0, 0);
        }
#pragma unroll
        for (int qa = 0; qa < 2; ++qa) {
          const float p0 = __builtin_amdgcn_exp2f(s4[qa][0]);
          const float p1 = __builtin_amdgcn_exp2f(s4[qa][1]);
          const float p2 = __builtin_amdgcn_exp2f(s4[qa][2]);
          const float p3 = __builtin_amdgcn_exp2f(s4[qa][3]);
          l_r[qa] += (p0 + p1) + (p2 + p3);
          unsigned int lo, hi;
          asm("v_cvt_pk_bf16_f32 %0, %1, %2" : "=v"(lo) : "v"(p0), "v"(p1));
          asm("v_cvt_pk_bf16_f32 %0, %1, %2" : "=v"(hi) : "v"(p2), "v"(p3));
          uint2 pk;
          pk.x = lo; pk.y = hi;
          *(uint2*)&Ps[w][qa * 16 + l15][f * 16 + quad * 4] = pk;
        }
      }
    } else {
      // LAST partial chunk: guarded path (slots >= nk produce P = 0)
#pragma unroll
      for (int f = 0; f < 4; ++f) {
        const bh8 a0 = *(const bh8*)&Ks[f * 16 + l15][quad * 8];
        const bh8 a1 = *(const bh8*)&Ks[f * 16 + l15][32 + quad * 8];
        f32x4 s4[2];
#pragma unroll
        for (int qa = 0; qa < 2; ++qa) {
          s4[qa] = (f32x4){0.f, 0.f, 0.f, 0.f};
          s4[qa] = __builtin_amdgcn_mfma_f32_16x16x32_bf16(a0, qf[qa][0], s4[qa], 0, 0, 0);
          s4[qa] = __builtin_amdgcn_mfma_f32_16x16x32_bf16(a1, qf[qa][1], s4[qa], 0, 0, 0);
        }
        const int keyb = kc * 64 + f * 16 + quad * 4;
#pragma unroll
        for (int qa = 0; qa < 2; ++qa) {
          const float p0 = (keyb + 0 < nk) ? __builtin_amdgcn_exp2f(s4[qa][0]) : 0.f;
          const float p1 = (keyb + 1 < nk) ? __builtin_amdgcn_exp2f(s4[qa][1]) : 0.f;
          const float p2 = (keyb + 2 < nk) ? __builtin_amdgcn_exp2f(s4[qa][2]) : 0.f;
          const float p3 = (keyb + 3 < nk) ? __builtin_amdgcn_exp2f(s4[qa][3]) : 0.f;
          l_r[qa] += (p0 + p1) + (p2 + p3);
          unsigned int lo, hi;
          asm("v_cvt_pk_bf16_f32 %0, %1, %2" : "=v"(lo) : "v"(p0), "v"(p1));
          asm("v_cvt_pk_bf16_f32 %0, %1, %2" : "=v"(hi) : "v"(p2), "v"(p3));
          uint2 pk;
          pk.x = lo; pk.y = hi;
          *(uint2*)&Ps[w][qa * 16 + l15][f * 16 + quad * 4] = pk;
        }
      }
    }

    bh8 pa[2][2];
#pragma unroll
    for (int qa = 0; qa < 2; ++qa) {
      pa[qa][0] = *(const bh8*)&Ps[w][qa * 16 + l15][quad * 8];
      pa[qa][1] = *(const bh8*)&Ps[w][qa * 16 + l15][32 + quad * 8];
    }
#pragma unroll
    for (int db = 0; db < 4; ++db) {
      const bh8 b0 = *(const bh8*)&Vs[db * 16 + l15][quad * 8];
      const bh8 b1 = *(const bh8*)&Vs[db * 16 + l15][32 + quad * 8];
#pragma unroll
      for (int qa = 0; qa < 2; ++qa) {
        oacc[qa][db] = __builtin_amdgcn_mfma_f32_16x16x32_bf16(pa[qa][0], b0, oacc[qa][db], 0, 0, 0);
        oacc[qa][db] = __builtin_amdgcn_mfma_f32_16x16x32_bf16(pa[qa][1], b1, oacc[qa][db], 0, 0, 0);
      }
    }
  }

  const int sh = slice * 6 + h;
#pragma unroll
  for (int qa = 0; qa < 2; ++qa) {
    l_r[qa] += __shfl_xor(l_r[qa], 16);       // hoisted cross-quad reduce
    l_r[qa] += __shfl_xor(l_r[qa], 32);
    const int qg = q0 + w * 32 + qa * 16;
#pragma unroll
    for (int db = 0; db < 4; ++db)
#pragma unroll
      for (int r = 0; r < 4; ++r) {
        const int q = qg + quad * 4 + r;
        if (q < N_TOK)
          Opart[((size_t)sh * NKPAD + q) * 64 + db * 16 + l15] = f2bf(oacc[qa][db][r]);
      }
    if (quad == 0) {
      const int q = qg + l15;
      if (q < N_TOK) Lpart[sh * NKPAD + q] = l_r[qa];
    }
  }

  // ---- fused merge: last arriver per (qtile, h) reduces all slices -> Am
  __shared__ int is_last;
  __threadfence();                            // release our partials
  __syncthreads();
  if (t == 0) {
    const int old = atomicAdd(&mergeCnt[blockIdx.x * 6 + h], 1);
    is_last = ((old + 1) % NSLICE == 0);      // replay-robust modulo form
  }
  __syncthreads();
  if (!is_last) return;
  __threadfence();                            // acquire other slices' writes
  for (int idx = t; idx < 2048; idx += 512) { // 256 q-rows x 8 u8-chunks
    const int q = q0 + (idx >> 3), d0 = (idx & 7) * 8;
    if (q >= N_TOK) break;
    float l = 0.f;
#pragma unroll
    for (int s = 0; s < NSLICE; ++s) l += Lpart[(s * 6 + h) * NKPAD + q];
    const float invl = 1.f / l;
    float o[8] = {0.f, 0.f, 0.f, 0.f, 0.f, 0.f, 0.f, 0.f};
#pragma unroll
    for (int s = 0; s < NSLICE; ++s) {
      const u8 v = *(const u8*)&Opart[((size_t)(s * 6 + h) * NKPAD + q) * 64 + d0];
#pragma unroll
      for (int j = 0; j < 8; ++j) o[j] += bf2f(v[j]);
    }
    u8 r8;
#pragma unroll
    for (int j = 0; j < 8; ++j) r8[j] = f2bf(o[j] * invl);
    *(u8*)&Am[(size_t)q * C_DIM + h * 64 + d0] = r8;
  }
}

// ---------------------------------------------------------------------------
extern "C" void kernel_launch(void* const* d_in, const int* in_sizes, int n_in,
                              void* d_out, int out_size, void* d_ws, size_t ws_size,
                              hipStream_t stream) {
  const float* x          = (const float*)d_in[0];
  const float* pos        = (const float*)d_in[1];
  const float* mask       = (const float*)d_in[2];
  const float* mask_block = (const float*)d_in[3];
  const float* Wq         = (const float*)d_in[4];
  const float* Wk         = (const float*)d_in[5];
  const float* Wv         = (const float*)d_in[6];
  const float* Wp         = (const float*)d_in[7];
  const float* bp         = (const float*)d_in[8];
  float* out = (float*)d_out;
  char* wsb = (char*)d_ws;

  float*  pooled_part = (float*)wsb;                // [64][384]
  float*  cnt_part    = (float*)(wsb + 98304);      // [64]
  int*    nk          = (int*)(wsb + 98560);
  int*    inv         = (int*)(wsb + 99072);        // [4099]
  ushort* Ak          = (ushort*)(wsb + 115712);    // [4160][384]
  ushort* Av          = (ushort*)(wsb + 3310592);   // [4160][384]
  ushort* Wb          = (ushort*)(wsb + 6505472);   // [4][384][384]
  ushort* Qh          = (ushort*)(wsb + 7685120);   // [6][4098][64]
  ushort* Kc          = (ushort*)(wsb + 10832384);  // [6][4160][64]
  ushort* Vt          = (ushort*)(wsb + 14027264);  // [6][64][4160]
  ushort* Am          = (ushort*)(wsb + 17222144);  // [4160][384]
  ushort* Op          = (ushort*)(wsb + 20417024);  // [30][4160][64]
  float*  Lp          = (float*)(wsb + 36391424);   // [30][4160]
  int*    mergeCnt    = (int*)(wsb + 36890624);     // [17][6]

  prep_kernel<<<dim3(357), dim3(256), 0, stream>>>(x, pos, Wq, Wk, Wv, Wp,
                                                   mask, mask_block, Ak, Av,
                                                   Wb, nk, inv,
                                                   pooled_part, cnt_part,
                                                   mergeCnt);
  gemm3_kernel<<<dim3(65, 18), 256, 0, stream>>>(Ak, Av, Wb, inv,
                                                 pooled_part, cnt_part, pos,
                                                 Qh, Kc, Vt);
  attn_kernel<<<dim3(17, 6, NSLICE), 512, 0, stream>>>(Qh, Kc, Vt, nk, Op, Lp,
                                                       mergeCnt, Am);
  gemm_out_kernel<<<dim3(65, 6), 256, 0, stream>>>(Am, Wb + 3 * 147456, bp, out);
}

// Round 14
// 142.052 us; speedup vs baseline: 2.0664x; 2.0664x over previous
//
#include <hip/hip_runtime.h>
#include <math.h>

#define N_TOK 4098
#define NK_TOK 4099
#define C_DIM 384
#define NKPAD 4160
#define NSLICE 5
// HEADS = 6, HD = 64

typedef short  bh8 __attribute__((ext_vector_type(8)));   // 8 bf16 (4 VGPRs)
typedef float  f32x4 __attribute__((ext_vector_type(4)));
typedef unsigned short ushort;
typedef ushort u4 __attribute__((ext_vector_type(4)));
typedef ushort u8 __attribute__((ext_vector_type(8)));

static __device__ __forceinline__ ushort f2bf(float f) {
  unsigned int u = __float_as_uint(f);
  u = (u + 0x7FFF + ((u >> 16) & 1)) >> 16;   // RNE
  return (ushort)u;
}
static __device__ __forceinline__ float bf2f(ushort s) {
  return __uint_as_float(((unsigned int)s) << 16);
}

// Q scale: D^-0.5 * log2(e), folded into Wq at prep; attention exp = exp2
#define QSCALE 0.18033688011112042f

// ---------------------------------------------------------------------------
// prep: blocks 0..259 build bf16 Ak/Av rows (16 rows each; row 4098 computed
// by the 12 gemm3 blocks that consume it); blocks 260..291 convert W
// (Wq prescaled by QSCALE); block 292: keep-compaction prefix scan ->
// inv[], nk; blocks 293..356: pool partials (64 rows each).
__global__ __launch_bounds__(256) void prep_kernel(
    const float* __restrict__ x, const float* __restrict__ pos,
    const float* __restrict__ Wq, const float* __restrict__ Wk,
    const float* __restrict__ Wv, const float* __restrict__ Wp,
    const float* __restrict__ mask, const float* __restrict__ mask_block,
    ushort* __restrict__ Ak, ushort* __restrict__ Av,
    ushort* __restrict__ Wb, int* __restrict__ nk, int* __restrict__ inv,
    float* __restrict__ pooled_part, float* __restrict__ cnt_part) {
  const int b = blockIdx.x, t = threadIdx.x;
  if (b < 260) {
    const int r0 = b * 16;
#pragma unroll
    for (int i = 0; i < 6; ++i) {
      const int idx = i * 1024 + t * 4;
      const int row = r0 + idx / C_DIM, col = idx % C_DIM;
      if (row >= NK_TOK - 1) continue;       // row 4098 computed in gemm3
      const float4 pv = *(const float4*)&pos[(size_t)row * C_DIM + col];
      const float4 xv = *(const float4*)&x[(size_t)row * C_DIM + col];
      u4 k4 = {f2bf(xv.x + pv.x), f2bf(xv.y + pv.y),
               f2bf(xv.z + pv.z), f2bf(xv.w + pv.w)};
      *(u4*)&Ak[(size_t)row * C_DIM + col] = k4;
      u4 v4 = {f2bf(xv.x), f2bf(xv.y), f2bf(xv.z), f2bf(xv.w)};
      *(u4*)&Av[(size_t)row * C_DIM + col] = v4;
    }
  } else if (b < 292) {
    const int wi = b - 260;                  // 0..31; 8 blocks per weight
    const float* src = (wi < 8) ? Wq : (wi < 16) ? Wk : (wi < 24) ? Wv : Wp;
    const float sc = (wi < 8) ? QSCALE : 1.f;  // fold Q prescale into Wq
    const int base = (wi >> 3) * 147456 + (wi & 7) * 18432;
#pragma unroll 2
    for (int i = 0; i < 18; ++i) {
      const int g = base + i * 1024 + t * 4;
      const float4 v = *(const float4*)&src[(wi & 7) * 18432 + i * 1024 + t * 4];
      u4 o = {f2bf(v.x * sc), f2bf(v.y * sc), f2bf(v.z * sc), f2bf(v.w * sc)};
      *(u4*)&Wb[g] = o;
    }
  } else if (b == 292) {
    // keep-compaction: 256 threads x 17 elements, block prefix scan
    __shared__ int scnt[256];
    const int j0 = t * 17;
    unsigned int bits = 0;
    int c = 0;
#pragma unroll 1
    for (int u = 0; u < 17; ++u) {
      const int j = j0 + u;
      bool keep = false;
      if (j < NK_TOK)
        keep = (j >= 1 && j <= N_TOK - 2) ? (mask[j - 1] >= 0.5f)
                                          : (mask_block[j] >= 0.5f);
      if (keep) { bits |= 1u << u; ++c; }
    }
    scnt[t] = c;
    __syncthreads();
    for (int d = 1; d < 256; d <<= 1) {
      const int v = scnt[t];
      const int add = (t >= d) ? scnt[t - d] : 0;
      __syncthreads();
      scnt[t] = v + add;
      __syncthreads();
    }
    int base = scnt[t] - c;                  // exclusive prefix
    if (t == 255) *nk = scnt[255];
#pragma unroll 1
    for (int u = 0; u < 17; ++u) {
      const int j = j0 + u;
      if (j < NK_TOK) inv[j] = ((bits >> u) & 1) ? base++ : -1;
    }
  } else {
    // pool partials: 64 blocks x 64 mask-rows; threads 0..127 cover 2 chans
    const int pb = b - 293;
    const int r0 = pb * 64;
    float acc0 = 0.f, acc1 = 0.f;
    int lc = 0;
    for (int r = r0; r < r0 + 64; ++r) {
      if (mask[r] < 0.5f) {
        acc0 += x[(size_t)(r + 1) * C_DIM + t];
        if (t < 128) acc1 += x[(size_t)(r + 1) * C_DIM + 256 + t];
        ++lc;
      }
    }
    pooled_part[pb * C_DIM + t] = acc0;
    if (t < 128) pooled_part[pb * C_DIM + 256 + t] = acc1;
    if (t == 0) cnt_part[pb] = (float)lc;
  }
}

// ---------------------------------------------------------------------------
// bf16 MFMA GEMM core: 64x64 out tile, K=384, BK=64, synchronous u8 staging
// with VGPR prefetch of the next K-chunk during compute. Padded LDS [64][72].
static __device__ __forceinline__ void gemm_core(
    const ushort* __restrict__ A, const ushort* __restrict__ B,
    ushort (* __restrict__ As)[72], ushort (* __restrict__ Bs)[72],
    int t, int w, int quad, int l15, f32x4 acc[4]) {
  const int g = t & 7;
  u8 ra[2], rb[2];
#pragma unroll
  for (int it = 0; it < 2; ++it) {
    const int r = it * 32 + (t >> 3);
    ra[it] = *(const u8*)&A[r * C_DIM + g * 8];
    rb[it] = *(const u8*)&B[r * C_DIM + g * 8];
  }
#pragma unroll 1
  for (int kt = 0; kt < 6; ++kt) {
    __syncthreads();                         // previous chunk's readers done
#pragma unroll
    for (int it = 0; it < 2; ++it) {
      const int r = it * 32 + (t >> 3);
      *(u8*)&As[r][g * 8] = ra[it];
      *(u8*)&Bs[r][g * 8] = rb[it];
    }
    __syncthreads();
    if (kt < 5) {
      const int k0 = (kt + 1) * 64;
#pragma unroll
      for (int it = 0; it < 2; ++it) {
        const int r = it * 32 + (t >> 3);
        ra[it] = *(const u8*)&A[r * C_DIM + k0 + g * 8];
        rb[it] = *(const u8*)&B[r * C_DIM + k0 + g * 8];
      }
    }
    const bh8 b0 = *(const bh8*)&Bs[w * 16 + l15][quad * 8];
    const bh8 b1 = *(const bh8*)&Bs[w * 16 + l15][32 + quad * 8];
#pragma unroll
    for (int mb = 0; mb < 4; ++mb) {
      const bh8 a0 = *(const bh8*)&As[mb * 16 + l15][quad * 8];
      const bh8 a1 = *(const bh8*)&As[mb * 16 + l15][32 + quad * 8];
      acc[mb] = __builtin_amdgcn_mfma_f32_16x16x32_bf16(a0, b0, acc[mb], 0, 0, 0);
      acc[mb] = __builtin_amdgcn_mfma_f32_16x16x32_bf16(a1, b1, acc[mb], 0, 0, 0);
    }
  }
}

// fused Q/K/V projection. y = which*6 + h. Q uses Ak with QSCALE-folded Wq.
// The 12 blocks (x==64, which>=1) that consume Ak/Av row 4098 compute the
// back token themselves in a prologue, write it to global, then
// __syncthreads (drains vmcnt -> own-block L2 visibility) before staging.
// Q-pass blocks read poison in row 4098 -- row-local in MFMA, dropped by
// the m<N_TOK store guard (same property rows 4099..4159 rely on).
// K epilogue scatters compacted rows via inv[]; V writes transposed Vt.
__global__ __launch_bounds__(256) void gemm3_kernel(
    ushort* __restrict__ Ak, ushort* __restrict__ Av,
    const ushort* __restrict__ Wb, const int* __restrict__ inv,
    const float* __restrict__ pooled_part, const float* __restrict__ cnt_part,
    const float* __restrict__ pos,
    ushort* __restrict__ Qh, ushort* __restrict__ Kc, ushort* __restrict__ Vt) {
  __shared__ ushort As[64][72], Bs[64][72];
  const int t = threadIdx.x, w = t >> 6, lane = t & 63;
  const int quad = lane >> 4, l15 = lane & 15;
  const int m0 = blockIdx.x * 64;
  const int which = blockIdx.y / 6, h = blockIdx.y % 6;

  if (blockIdx.x == 64 && which >= 1) {      // back token -> row 4098
    float cs = 0.f;
#pragma unroll
    for (int p = 0; p < 64; ++p) cs += cnt_part[p];
    const float ic = 1.f / (cs + 1e-10f);
    for (int c = t; c < C_DIM; c += 256) {
      float s = 0.f;
      for (int p = 0; p < 64; ++p) s += pooled_part[p * C_DIM + c];
      const float back = s * ic;
      const size_t off = (size_t)(NK_TOK - 1) * C_DIM + c;
      if (which == 1) Ak[off] = f2bf(back + pos[off]);
      else            Av[off] = f2bf(back);
    }
    __syncthreads();                         // writes visible to own staging
  }

  const ushort* A = (which == 2 ? Av : Ak) + (size_t)m0 * C_DIM;
  const ushort* B = Wb + (size_t)which * 147456 + (size_t)h * 64 * C_DIM;
  f32x4 acc[4];
#pragma unroll
  for (int i = 0; i < 4; ++i) acc[i] = (f32x4){0.f, 0.f, 0.f, 0.f};
  gemm_core(A, B, As, Bs, t, w, quad, l15, acc);
  const int n = w * 16 + l15;
  if (which == 0) {
#pragma unroll
    for (int mb = 0; mb < 4; ++mb)
#pragma unroll
      for (int r = 0; r < 4; ++r) {
        const int m = m0 + mb * 16 + quad * 4 + r;
        if (m < N_TOK) Qh[((size_t)h * N_TOK + m) * 64 + n] = f2bf(acc[mb][r]);
      }
  } else if (which == 1) {
#pragma unroll
    for (int mb = 0; mb < 4; ++mb)
#pragma unroll
      for (int r = 0; r < 4; ++r) {
        const int m = m0 + mb * 16 + quad * 4 + r;
        if (m < NK_TOK) {
          const int slot = inv[m];
          if (slot >= 0) Kc[((size_t)h * NKPAD + slot) * 64 + n] = f2bf(acc[mb][r]);
        }
      }
  } else {
    // V: write transposed layout [h][d=n][slot] directly (fused vtrans)
#pragma unroll
    for (int mb = 0; mb < 4; ++mb)
#pragma unroll
      for (int r = 0; r < 4; ++r) {
        const int m = m0 + mb * 16 + quad * 4 + r;
        if (m < NK_TOK) {
          const int slot = inv[m];
          if (slot >= 0) Vt[((size_t)h * 64 + n) * NKPAD + slot] = f2bf(acc[mb][r]);
        }
      }
  }
}

// output projection: fp32 out + bias
__global__ __launch_bounds__(256) void gemm_out_kernel(
    const ushort* __restrict__ Am, const ushort* __restrict__ Wpb,
    const float* __restrict__ bp, float* __restrict__ out) {
  __shared__ ushort As[64][72], Bs[64][72];
  const int t = threadIdx.x, w = t >> 6, lane = t & 63;
  const int quad = lane >> 4, l15 = lane & 15;
  const int m0 = blockIdx.x * 64;
  const int h = blockIdx.y;
  f32x4 acc[4];
#pragma unroll
  for (int i = 0; i < 4; ++i) acc[i] = (f32x4){0.f, 0.f, 0.f, 0.f};
  gemm_core(Am + (size_t)m0 * C_DIM, Wpb + (size_t)h * 64 * C_DIM,
            As, Bs, t, w, quad, l15, acc);
  const int n = w * 16 + l15;
  const float bb = bp[h * 64 + n];
#pragma unroll
  for (int mb = 0; mb < 4; ++mb)
#pragma unroll
    for (int r = 0; r < 4; ++r) {
      const int m = m0 + mb * 16 + quad * 4 + r;
      if (m < N_TOK) out[(size_t)m * C_DIM + h * 64 + n] = acc[mb][r] + bb;
    }
}

// ---------------------------------------------------------------------------
// MFMA flash attention: 8 waves x 32 q = 256 q per block (R12 structure:
// full-chunk unguarded softmax fast path) + csum shuffle-reduce hoisted out
// of the chunk loop (per-lane partials, one reduce in epilogue). R13's
// fused cross-block merge REVERTED: its per-block device-scope
// __threadfence (L2 writeback + vmcnt(0) drain for cross-XCD visibility)
// serialized the memory system (attn 195us, all pipes idle). Separate
// merge_kernel restored. grid (17 q-tiles of 256, 6 heads, NSLICE=5).
__global__ __launch_bounds__(512) void attn_kernel(
    const ushort* __restrict__ Qh, const ushort* __restrict__ Kc,
    const ushort* __restrict__ Vt, const int* __restrict__ nkp,
    ushort* __restrict__ Opart, float* __restrict__ Lpart) {
  __shared__ ushort Ks[64][72];      // [slot][d]
  __shared__ ushort Vs[64][72];      // [d][slot]
  __shared__ ushort Ps[8][32][72];   // per-wave P^T staging, 2 q-frags
  const int t = threadIdx.x, w = t >> 6, lane = t & 63;
  const int quad = lane >> 4, l15 = lane & 15;
  const int h = blockIdx.y, slice = blockIdx.z;
  const int q0 = blockIdx.x * 256;
  const int nk = *nkp, nchunk = (nk + 63) >> 6;
  const int g = t & 7;
  const int sr = t >> 3;             // 0..63 staging row (512 threads)

  bh8 qf[2][2];
#pragma unroll
  for (int qa = 0; qa < 2; ++qa) {
    int qr = q0 + w * 32 + qa * 16 + l15;
    if (qr > N_TOK - 1) qr = N_TOK - 1;      // clamp (stores guarded)
    const ushort* qp = Qh + ((size_t)h * N_TOK + qr) * 64 + quad * 8;
    qf[qa][0] = *(const bh8*)qp;
    qf[qa][1] = *(const bh8*)(qp + 32);
  }
  f32x4 oacc[2][4];
#pragma unroll
  for (int qa = 0; qa < 2; ++qa)
#pragma unroll
    for (int i = 0; i < 4; ++i) oacc[qa][i] = (f32x4){0.f, 0.f, 0.f, 0.f};
  float l_r[2] = {0.f, 0.f};         // per-lane partials; reduced in epilogue

  const ushort* kb = Kc + (size_t)h * NKPAD * 64;
  const ushort* vb = Vt + (size_t)h * 64 * NKPAD;

  // loop-carried staging pointers (strength-reduced addressing)
  const ushort* kstage = kb + ((size_t)slice * 64 + sr) * 64 + g * 8;
  const ushort* vstage = vb + (size_t)sr * NKPAD + slice * 64 + g * 8;

  u8 rk, rv;
  if (slice < nchunk) {
    rk = *(const u8*)kstage;
    rv = *(const u8*)vstage;
  }
#pragma unroll 1
  for (int kc = slice; kc < nchunk; kc += NSLICE) {
    __syncthreads();                          // previous chunk's readers done
    *(u8*)&Ks[sr][g * 8] = rk;
    *(u8*)&Vs[sr][g * 8] = rv;
    __syncthreads();
    if (kc + NSLICE < nchunk) {               // prefetch next chunk into VGPRs
      kstage += NSLICE * 64 * 64;
      vstage += NSLICE * 64;
      rk = *(const u8*)kstage;
      rv = *(const u8*)vstage;
    }
    if ((kc + 1) * 64 <= nk) {
      // FULL chunk (all 64 slots valid): unguarded softmax fast path
#pragma unroll
      for (int f = 0; f < 4; ++f) {
        const bh8 a0 = *(const bh8*)&Ks[f * 16 + l15][quad * 8];
        const bh8 a1 = *(const bh8*)&Ks[f * 16 + l15][32 + quad * 8];
        f32x4 s4[2];
#pragma unroll
        for (int qa = 0; qa < 2; ++qa) {
          s4[qa] = (f32x4){0.f, 0.f, 0.f, 0.f};
          s4[qa] = __builtin_amdgcn_mfma_f32_16x16x32_bf16(a0, qf[qa][0], s4[qa], 0, 0, 0);
          s4[qa] = __builtin_amdgcn_mfma_f32_16x16x32_bf16(a1, qf[qa][1], s4[qa], 0, 0, 0);
        }
#pragma unroll
        for (int qa = 0; qa < 2; ++qa) {
          const float p0 = __builtin_amdgcn_exp2f(s4[qa][0]);
          const float p1 = __builtin_amdgcn_exp2f(s4[qa][1]);
          const float p2 = __builtin_amdgcn_exp2f(s4[qa][2]);
          const float p3 = __builtin_amdgcn_exp2f(s4[qa][3]);
          l_r[qa] += (p0 + p1) + (p2 + p3);
          unsigned int lo, hi;
          asm("v_cvt_pk_bf16_f32 %0, %1, %2" : "=v"(lo) : "v"(p0), "v"(p1));
          asm("v_cvt_pk_bf16_f32 %0, %1, %2" : "=v"(hi) : "v"(p2), "v"(p3));
          uint2 pk;
          pk.x = lo; pk.y = hi;
          *(uint2*)&Ps[w][qa * 16 + l15][f * 16 + quad * 4] = pk;
        }
      }
    } else {
      // LAST partial chunk: guarded path (slots >= nk produce P = 0)
#pragma unroll
      for (int f = 0; f < 4; ++f) {
        const bh8 a0 = *(const bh8*)&Ks[f * 16 + l15][quad * 8];
        const bh8 a1 = *(const bh8*)&Ks[f * 16 + l15][32 + quad * 8];
        f32x4 s4[2];
#pragma unroll
        for (int qa = 0; qa < 2; ++qa) {
          s4[qa] = (f32x4){0.f, 0.f, 0.f, 0.f};
          s4[qa] = __builtin_amdgcn_mfma_f32_16x16x32_bf16(a0, qf[qa][0], s4[qa], 0, 0, 0);
          s4[qa] = __builtin_amdgcn_mfma_f32_16x16x32_bf16(a1, qf[qa][1], s4[qa], 0, 0, 0);
        }
        const int keyb = kc * 64 + f * 16 + quad * 4;
#pragma unroll
        for (int qa = 0; qa < 2; ++qa) {
          const float p0 = (keyb + 0 < nk) ? __builtin_amdgcn_exp2f(s4[qa][0]) : 0.f;
          const float p1 = (keyb + 1 < nk) ? __builtin_amdgcn_exp2f(s4[qa][1]) : 0.f;
          const float p2 = (keyb + 2 < nk) ? __builtin_amdgcn_exp2f(s4[qa][2]) : 0.f;
          const float p3 = (keyb + 3 < nk) ? __builtin_amdgcn_exp2f(s4[qa][3]) : 0.f;
          l_r[qa] += (p0 + p1) + (p2 + p3);
          unsigned int lo, hi;
          asm("v_cvt_pk_bf16_f32 %0, %1, %2" : "=v"(lo) : "v"(p0), "v"(p1));
          asm("v_cvt_pk_bf16_f32 %0, %1, %2" : "=v"(hi) : "v"(p2), "v"(p3));
          uint2 pk;
          pk.x = lo; pk.y = hi;
          *(uint2*)&Ps[w][qa * 16 + l15][f * 16 + quad * 4] = pk;
        }
      }
    }

    bh8 pa[2][2];
#pragma unroll
    for (int qa = 0; qa < 2; ++qa) {
      pa[qa][0] = *(const bh8*)&Ps[w][qa * 16 + l15][quad * 8];
      pa[qa][1] = *(const bh8*)&Ps[w][qa * 16 + l15][32 + quad * 8];
    }
#pragma unroll
    for (int db = 0; db < 4; ++db) {
      const bh8 b0 = *(const bh8*)&Vs[db * 16 + l15][quad * 8];
      const bh8 b1 = *(const bh8*)&Vs[db * 16 + l15][32 + quad * 8];
#pragma unroll
      for (int qa = 0; qa < 2; ++qa) {
        oacc[qa][db] = __builtin_amdgcn_mfma_f32_16x16x32_bf16(pa[qa][0], b0, oacc[qa][db], 0, 0, 0);
        oacc[qa][db] = __builtin_amdgcn_mfma_f32_16x16x32_bf16(pa[qa][1], b1, oacc[qa][db], 0, 0, 0);
      }
    }
  }

  const int sh = slice * 6 + h;
#pragma unroll
  for (int qa = 0; qa < 2; ++qa) {
    l_r[qa] += __shfl_xor(l_r[qa], 16);       // hoisted cross-quad reduce
    l_r[qa] += __shfl_xor(l_r[qa], 32);
    const int qg = q0 + w * 32 + qa * 16;
#pragma unroll
    for (int db = 0; db < 4; ++db)
#pragma unroll
      for (int r = 0; r < 4; ++r) {
        const int q = qg + quad * 4 + r;
        if (q < N_TOK)
          Opart[((size_t)sh * NKPAD + q) * 64 + db * 16 + l15] = f2bf(oacc[qa][db][r]);
      }
    if (quad == 0) {
      const int q = qg + l15;
      if (q < N_TOK) Lpart[sh * NKPAD + q] = l_r[qa];
    }
  }
}

// merge NSLICE key-slice partials -> bf16 Am [4160][384]
__global__ __launch_bounds__(256) void merge_kernel(const ushort* __restrict__ Opart,
                                                    const float* __restrict__ Lpart,
                                                    ushort* __restrict__ Am) {
  const int idx = blockIdx.x * 256 + threadIdx.x;     // u8 chunk index
  if (idx >= N_TOK * 48) return;
  const int q = idx / 48, c = (idx % 48) * 8;
  const int h = c >> 6, d = c & 63;
  float l = 0.f;
#pragma unroll
  for (int s = 0; s < NSLICE; ++s) l += Lpart[(s * 6 + h) * NKPAD + q];
  const float inv = 1.f / l;
  float o[8] = {0.f, 0.f, 0.f, 0.f, 0.f, 0.f, 0.f, 0.f};
#pragma unroll
  for (int s = 0; s < NSLICE; ++s) {
    const u8 v = *(const u8*)&Opart[((size_t)(s * 6 + h) * NKPAD + q) * 64 + d];
#pragma unroll
    for (int j = 0; j < 8; ++j) o[j] += bf2f(v[j]);
  }
  u8 r;
#pragma unroll
  for (int j = 0; j < 8; ++j) r[j] = f2bf(o[j] * inv);
  *(u8*)&Am[(size_t)q * C_DIM + c] = r;
}

// ---------------------------------------------------------------------------
extern "C" void kernel_launch(void* const* d_in, const int* in_sizes, int n_in,
                              void* d_out, int out_size, void* d_ws, size_t ws_size,
                              hipStream_t stream) {
  const float* x          = (const float*)d_in[0];
  const float* pos        = (const float*)d_in[1];
  const float* mask       = (const float*)d_in[2];
  const float* mask_block = (const float*)d_in[3];
  const float* Wq         = (const float*)d_in[4];
  const float* Wk         = (const float*)d_in[5];
  const float* Wv         = (const float*)d_in[6];
  const float* Wp         = (const float*)d_in[7];
  const float* bp         = (const float*)d_in[8];
  float* out = (float*)d_out;
  char* wsb = (char*)d_ws;

  float*  pooled_part = (float*)wsb;                // [64][384]
  float*  cnt_part    = (float*)(wsb + 98304);      // [64]
  int*    nk          = (int*)(wsb + 98560);
  int*    inv         = (int*)(wsb + 99072);        // [4099]
  ushort* Ak          = (ushort*)(wsb + 115712);    // [4160][384]
  ushort* Av          = (ushort*)(wsb + 3310592);   // [4160][384]
  ushort* Wb          = (ushort*)(wsb + 6505472);   // [4][384][384]
  ushort* Qh          = (ushort*)(wsb + 7685120);   // [6][4098][64]
  ushort* Kc          = (ushort*)(wsb + 10832384);  // [6][4160][64]
  ushort* Vt          = (ushort*)(wsb + 14027264);  // [6][64][4160]
  ushort* Am          = (ushort*)(wsb + 17222144);  // [4160][384]
  ushort* Op          = (ushort*)(wsb + 20417024);  // [30][4160][64]
  float*  Lp          = (float*)(wsb + 36391424);   // [30][4160]

  prep_kernel<<<dim3(357), dim3(256), 0, stream>>>(x, pos, Wq, Wk, Wv, Wp,
                                                   mask, mask_block, Ak, Av,
                                                   Wb, nk, inv,
                                                   pooled_part, cnt_part);
  gemm3_kernel<<<dim3(65, 18), 256, 0, stream>>>(Ak, Av, Wb, inv,
                                                 pooled_part, cnt_part, pos,
                                                 Qh, Kc, Vt);
  attn_kernel<<<dim3(17, 6, NSLICE), 512, 0, stream>>>(Qh, Kc, Vt, nk, Op, Lp);
  merge_kernel<<<dim3(769), 256, 0, stream>>>(Op, Lp, Am);
  gemm_out_kernel<<<dim3(65, 6), 256, 0, stream>>>(Am, Wb + 3 * 147456, bp, out);
}